// Round 1
// 1495.542 us; speedup vs baseline: 1.1169x; 1.1169x over previous
//
#include <hip/hip_runtime.h>
#include <stdint.h>

#define DEVI __device__ __forceinline__

typedef float f32x4 __attribute__((ext_vector_type(4)));
typedef __bf16 bf16x8 __attribute__((ext_vector_type(8)));

DEVI ushort f2b(float f) {
  uint32_t x = __float_as_uint(f);
  uint32_t r = (x + 0x7fffu + ((x >> 16) & 1u)) >> 16;
  return (ushort)r;
}
DEVI float b2f(ushort u) { return __uint_as_float(((uint32_t)u) << 16); }

DEVI void async_cp16(const void* g, void* l) {
  __builtin_amdgcn_global_load_lds(
      (__attribute__((address_space(1))) void*)(uintptr_t)(g),
      (__attribute__((address_space(3))) void*)(uintptr_t)(l), 16, 0, 0);
}

DEVI f32x4 MF(bf16x8 a, bf16x8 b, f32x4 c) {
  return __builtin_amdgcn_mfma_f32_16x16x32_bf16(a, b, c, 0, 0, 0);
}

#define MFENCE asm volatile("" ::: "memory")
#define BARRIER                       \
  do {                                \
    MFENCE;                           \
    __builtin_amdgcn_s_barrier();     \
    MFENCE;                           \
  } while (0)

// ---------------- elementwise helpers ----------------

__global__ void f32_to_bf16(const float* __restrict__ s, ushort* __restrict__ d, int n4) {
  int stride = gridDim.x * blockDim.x;
  for (int i = blockIdx.x * blockDim.x + threadIdx.x; i < n4; i += stride) {
    float4 v = ((const float4*)s)[i];
    ushort4 o;
    o.x = f2b(v.x); o.y = f2b(v.y); o.z = f2b(v.z); o.w = f2b(v.w);
    ((ushort4*)d)[i] = o;
  }
}

// mods[b,i,h] = sst[i,h] + temb[b,h];  n = 2*6*2048 = 24576
__global__ void mods_k(const float* __restrict__ sst, const float* __restrict__ temb,
                       float* __restrict__ mods) {
  int i = blockIdx.x * blockDim.x + threadIdx.x;
  int b = i / 12288;
  int rem = i - b * 12288;
  mods[i] = sst[rem] + temb[b * 2048 + (rem & 2047)];
}

// norm1 = bf16(hidden*(1+scale_msa)+shift_msa); one thread per 4 elems
__global__ void norm1_k(const float* __restrict__ hid, const float* __restrict__ mods,
                        ushort* __restrict__ out) {
  int i = blockIdx.x * blockDim.x + threadIdx.x;  // < 2097152
  int e = i * 4;
  int b = e >> 22;
  int h = e & 2047;
  float4 v = ((const float4*)hid)[i];
  const float* mb = mods + b * 12288;
  float4 sc = *(const float4*)(mb + 2048 + h);
  float4 sh = *(const float4*)(mb + h);
  ushort4 o;
  o.x = f2b(v.x * (1.f + sc.x) + sh.x);
  o.y = f2b(v.y * (1.f + sc.y) + sh.y);
  o.z = f2b(v.z * (1.f + sc.z) + sh.z);
  o.w = f2b(v.w * (1.f + sc.w) + sh.w);
  ((ushort4*)out)[i] = o;
}

// per-head layernorm on q and k halves of qkv (layout [token][4096]), in place.
__global__ __launch_bounds__(256) void qk_ln(ushort* __restrict__ qkv) {
  const int rid = blockIdx.x * 4 + (threadIdx.x >> 6);
  const int L = threadIdx.x & 63;
  const int half = rid >> 16;        // 0: q, 1: k (65536 rows each)
  const int r2 = rid & 65535;
  const int bs = r2 >> 4, head = r2 & 15;
  ushort* p = qkv + (size_t)bs * 4096 + half * 2048 + head * 128 + L * 2;
  uint32_t u = *(const uint32_t*)p;
  float e0 = b2f((ushort)(u & 0xffff));
  float e1 = b2f((ushort)(u >> 16));
  float s = e0 + e1;
#pragma unroll
  for (int d = 1; d < 64; d <<= 1) s += __shfl_xor(s, d);
  float mu = s * (1.0f / 128.0f);
  float d0 = e0 - mu, d1 = e1 - mu;
  float vq = d0 * d0 + d1 * d1;
#pragma unroll
  for (int d = 1; d < 64; d <<= 1) vq += __shfl_xor(vq, d);
  float rstd = rsqrtf(vq * (1.0f / 128.0f) + 1e-5f);
  uint32_t ou = (uint32_t)f2b(d0 * rstd) | ((uint32_t)f2b(d1 * rstd) << 16);
  *(uint32_t*)p = ou;
}

// ---------------- GEMM: C[m,n] = epi( sum_k A[m,k]*W[n,k] + bias ) ----------------
// block 256 = 4 waves; tile 128x128, BK=64; wave computes 64x64.
// (legacy path, kept for QKV/VT/ATTNOUT/FINAL shapes)

enum { EPI_QKV = 0, EPI_ATTNOUT = 1, EPI_GELU = 2, EPI_MULG = 3, EPI_FINAL = 4, EPI_VT = 5 };

template <int EPI>
__global__ __launch_bounds__(256) void gemm_bt(
    const ushort* __restrict__ A, int lda,
    const ushort* __restrict__ W, int ldw,
    const float* __restrict__ bias, int K,
    float* __restrict__ OF,
    ushort* __restrict__ OB, int ldob, int col0,
    const float* __restrict__ R0,
    const float* __restrict__ mods,
    const ushort* __restrict__ G) {
  __shared__ alignas(16) ushort As[128 * 64];
  __shared__ alignas(16) ushort Bs[128 * 64];
  const int tid = threadIdx.x;
  const int w = tid >> 6, L = tid & 63;
  const int r16 = L & 15, quad = L >> 4;
  const int m0 = blockIdx.y * 128, n0 = blockIdx.x * 128;

  f32x4 acc[4][4] = {};

  const ushort* Ag[4];
  const ushort* Bg[4];
  ushort* Al[4];
  ushort* Bl[4];
#pragma unroll
  for (int i = 0; i < 4; i++) {
    const int f = w * 4 + i, g = f >> 1, kf = f & 1;
    Ag[i] = A + (size_t)(m0 + g * 16 + r16) * lda + kf * 32 + quad * 8;
    Bg[i] = W + (size_t)(n0 + g * 16 + r16) * ldw + kf * 32 + quad * 8;
    Al[i] = &As[f * 512];
    Bl[i] = &Bs[f * 512];
  }

  const int abase = (w & 1) * 4096 + L * 8;
  const int bbase = (w >> 1) * 4096 + L * 8;

  for (int it = 0; it < K; it += 64) {
    __syncthreads();
#pragma unroll
    for (int i = 0; i < 4; i++) {
      async_cp16(Ag[i], Al[i]);
      async_cp16(Bg[i], Bl[i]);
      Ag[i] += 64;
      Bg[i] += 64;
    }
    __syncthreads();
#pragma unroll
    for (int kk = 0; kk < 2; kk++) {
      bf16x8 af[4], bfq[4];
#pragma unroll
      for (int i = 0; i < 4; i++) af[i] = *(const bf16x8*)&As[abase + (i * 2 + kk) * 512];
#pragma unroll
      for (int j = 0; j < 4; j++) bfq[j] = *(const bf16x8*)&Bs[bbase + (j * 2 + kk) * 512];
#pragma unroll
      for (int i = 0; i < 4; i++)
#pragma unroll
        for (int j = 0; j < 4; j++)
          acc[i][j] =
              __builtin_amdgcn_mfma_f32_16x16x32_bf16(af[i], bfq[j], acc[i][j], 0, 0, 0);
    }
  }

  const int wm = (w & 1) * 64, wn = (w >> 1) * 64;
#pragma unroll
  for (int ni = 0; ni < 4; ni++) {
    const int col = n0 + wn + ni * 16 + r16;
    const float bvc = bias[(EPI == EPI_VT) ? 0 : col];
#pragma unroll
    for (int mi = 0; mi < 4; mi++) {
#pragma unroll
      for (int r = 0; r < 4; r++) {
        const int row = m0 + wm + mi * 16 + quad * 4 + r;
        float v = acc[mi][ni][r] + ((EPI == EPI_VT) ? bias[row] : bvc);
        if (EPI == EPI_QKV) {
          OB[(size_t)row * ldob + col0 + col] = f2b(v);
        } else if (EPI == EPI_VT) {
          OB[(size_t)row * ldob + col] = f2b(v);
        } else if (EPI == EPI_ATTNOUT) {
          const int b = row >> 11;
          const float* mb = mods + b * 12288;
          float o = R0[(size_t)row * 2048 + col] + mb[2 * 2048 + col] * v;
          OF[(size_t)row * 2048 + col] = o;
          OB[(size_t)row * 2048 + col] =
              f2b(o * (1.0f + mb[4 * 2048 + col]) + mb[3 * 2048 + col]);
        } else if (EPI == EPI_GELU) {
          float x = v;
          float y = 0.7978845608028654f * (x + 0.044715f * x * x * x);
          float e = exp2f(-2.8853900817779268f * y);
          OB[(size_t)row * ldob + col] = f2b(x * __builtin_amdgcn_rcpf(1.0f + e));
        } else if (EPI == EPI_MULG) {
          float g = b2f(G[(size_t)row * ldob + col]);
          OB[(size_t)row * ldob + col] = f2b(v * g);
        } else {  // EPI_FINAL
          const int b = row >> 11;
          const float* mb = mods + b * 12288;
          size_t idx = (size_t)row * 2048 + col;
          OF[idx] = OF[idx] + mb[5 * 2048 + col] * v;
        }
      }
    }
  }
}

// ---------------- GEMM 256x256, 8-wave, deep pipeline (T2+T3+T4+T5) ----------------
// BM=BN=256, BK=64, 512 threads (8 waves, 2M x 4N), wave output 128x64.
// LDS 128 KiB: [dbuf 2][mat 2][half 2][kk 2][128 rows][32 ushorts] (16 slabs x 8 KiB).
// Swizzle: physical 16B-slot s within a row holds k-slot s ^ ((row>>1)&3); applied on
// the global SOURCE address (global_load_lds dest stays linear, rule #21) and on reads.
// Pipeline: per K-tile 4 phases {ds_read subtile; issue 2 gload_lds (tile t+1); barrier;
// setprio MFMA x16; barrier}; counted s_waitcnt vmcnt(4) after P1 (drains t.kk1) and
// after P3 (drains t+1.kk0) -- never 0 in the main loop. Prefetch depth ~1.5 K-tiles.

template <int EPI>
__global__ __launch_bounds__(512, 2) void gemm256(
    const ushort* __restrict__ A, int lda,
    const ushort* __restrict__ W, int ldw,
    const float* __restrict__ bias, int K,
    ushort* __restrict__ OB, int ldob,
    const ushort* __restrict__ G) {
  __shared__ alignas(16) ushort lds[65536];
  const int tid = threadIdx.x;
  const int w = tid >> 6, L = tid & 63;
  const int r16 = L & 15, quad = L >> 4;
  const int wm = w >> 2, wn = w & 3;
  const int m0 = blockIdx.y * 256, n0 = blockIdx.x * 256;

  // per-lane swizzle constants (independent of mi/ni/rg -- see derivation)
  const int sA = quad ^ ((r16 >> 1) & 3);            // read k-slot
  const int kswz = 8 * ((L & 3) ^ ((L >> 3) & 3));   // stage-source k-offset (elems)

  // read bases (ushort offsets; add cb + kk*4096 + frag*512)
  const int aoff = wm * 8192 + r16 * 32 + 8 * sA;
  const int boff = 16384 + (wn >> 1) * 8192 + (wn & 1) * 2048 + r16 * 32 + 8 * sA;

  // staging: 8 instrs/thread/K-tile: {0,1}=A.kk0 {2,3}=B.kk0 {4,5}=A.kk1 {6,7}=B.kk1
  const ushort* src[8];
  int ldst[8];
#pragma unroll
  for (int i = 0; i < 8; i++) {
    const int mat = (i >> 1) & 1, kk = i >> 2;
    const int j = w * 2 + (i & 1), half = j >> 3, rg = j & 7;
    const int grow = half * 128 + rg * 16 + (L >> 2);
    src[i] = (mat ? W + (size_t)(n0 + grow) * ldw : A + (size_t)(m0 + grow) * lda) +
             kk * 32 + kswz;
    ldst[i] = mat * 16384 + half * 8192 + kk * 4096 + rg * 512;
  }

  f32x4 acc[8][4] = {};
  const int NT = K >> 6;

  // prologue: tile 0 -> buf 0, full drain (one-time)
#pragma unroll
  for (int i = 0; i < 8; i++) {
    async_cp16(src[i], &lds[ldst[i]]);
    src[i] += 64;
  }
  asm volatile("s_waitcnt vmcnt(0)" ::: "memory");
  __builtin_amdgcn_s_barrier();
  MFENCE;

  for (int t = 0; t < NT - 1; ++t) {
    const int cb = (t & 1) << 15, nb = cb ^ 32768;
    const ushort* Ab = &lds[cb + aoff];
    const ushort* Bb = &lds[cb + boff];
    bf16x8 af[8], bq[2];

    // ---- P0: kk0, ni 0-1
#pragma unroll
    for (int mi = 0; mi < 8; mi++) af[mi] = *(const bf16x8*)(Ab + mi * 512);
    bq[0] = *(const bf16x8*)(Bb);
    bq[1] = *(const bf16x8*)(Bb + 512);
    async_cp16(src[0], &lds[nb + ldst[0]]); src[0] += 64;
    async_cp16(src[1], &lds[nb + ldst[1]]); src[1] += 64;
    BARRIER;
    __builtin_amdgcn_s_setprio(1);
#pragma unroll
    for (int mi = 0; mi < 8; mi++) {
      acc[mi][0] = MF(af[mi], bq[0], acc[mi][0]);
      acc[mi][1] = MF(af[mi], bq[1], acc[mi][1]);
    }
    __builtin_amdgcn_s_setprio(0);
    BARRIER;

    // ---- P1: kk0, ni 2-3
    bq[0] = *(const bf16x8*)(Bb + 1024);
    bq[1] = *(const bf16x8*)(Bb + 1536);
    async_cp16(src[2], &lds[nb + ldst[2]]); src[2] += 64;
    async_cp16(src[3], &lds[nb + ldst[3]]); src[3] += 64;
    BARRIER;
    __builtin_amdgcn_s_setprio(1);
#pragma unroll
    for (int mi = 0; mi < 8; mi++) {
      acc[mi][2] = MF(af[mi], bq[0], acc[mi][2]);
      acc[mi][3] = MF(af[mi], bq[1], acc[mi][3]);
    }
    __builtin_amdgcn_s_setprio(0);
    // drain t.kk1 (oldest 4 of 8 outstanding); t+1.kk0 stays in flight
    asm volatile("s_waitcnt vmcnt(4)" ::: "memory");
    __builtin_amdgcn_s_barrier();
    MFENCE;

    // ---- P2: kk1, ni 0-1
#pragma unroll
    for (int mi = 0; mi < 8; mi++) af[mi] = *(const bf16x8*)(Ab + 4096 + mi * 512);
    bq[0] = *(const bf16x8*)(Bb + 4096);
    bq[1] = *(const bf16x8*)(Bb + 4096 + 512);
    async_cp16(src[4], &lds[nb + ldst[4]]); src[4] += 64;
    async_cp16(src[5], &lds[nb + ldst[5]]); src[5] += 64;
    BARRIER;
    __builtin_amdgcn_s_setprio(1);
#pragma unroll
    for (int mi = 0; mi < 8; mi++) {
      acc[mi][0] = MF(af[mi], bq[0], acc[mi][0]);
      acc[mi][1] = MF(af[mi], bq[1], acc[mi][1]);
    }
    __builtin_amdgcn_s_setprio(0);
    BARRIER;

    // ---- P3: kk1, ni 2-3
    bq[0] = *(const bf16x8*)(Bb + 4096 + 1024);
    bq[1] = *(const bf16x8*)(Bb + 4096 + 1536);
    async_cp16(src[6], &lds[nb + ldst[6]]); src[6] += 64;
    async_cp16(src[7], &lds[nb + ldst[7]]); src[7] += 64;
    BARRIER;
    __builtin_amdgcn_s_setprio(1);
#pragma unroll
    for (int mi = 0; mi < 8; mi++) {
      acc[mi][2] = MF(af[mi], bq[0], acc[mi][2]);
      acc[mi][3] = MF(af[mi], bq[1], acc[mi][3]);
    }
    __builtin_amdgcn_s_setprio(0);
    // drain t+1.kk0 (oldest 4); t+1.kk1 stays in flight
    asm volatile("s_waitcnt vmcnt(4)" ::: "memory");
    __builtin_amdgcn_s_barrier();
    MFENCE;
  }

  // peeled last tile (no staging)
  {
    const int cb = ((NT - 1) & 1) << 15;
    const ushort* Ab = &lds[cb + aoff];
    const ushort* Bb = &lds[cb + boff];
    bf16x8 af[8], bq[4];
#pragma unroll
    for (int mi = 0; mi < 8; mi++) af[mi] = *(const bf16x8*)(Ab + mi * 512);
#pragma unroll
    for (int ni = 0; ni < 4; ni++) bq[ni] = *(const bf16x8*)(Bb + ni * 512);
#pragma unroll
    for (int mi = 0; mi < 8; mi++)
#pragma unroll
      for (int ni = 0; ni < 4; ni++) acc[mi][ni] = MF(af[mi], bq[ni], acc[mi][ni]);
    asm volatile("s_waitcnt vmcnt(0)" ::: "memory");
    __builtin_amdgcn_s_barrier();
    MFENCE;
#pragma unroll
    for (int mi = 0; mi < 8; mi++) af[mi] = *(const bf16x8*)(Ab + 4096 + mi * 512);
#pragma unroll
    for (int ni = 0; ni < 4; ni++) bq[ni] = *(const bf16x8*)(Bb + 4096 + ni * 512);
#pragma unroll
    for (int mi = 0; mi < 8; mi++)
#pragma unroll
      for (int ni = 0; ni < 4; ni++) acc[mi][ni] = MF(af[mi], bq[ni], acc[mi][ni]);
  }

  // epilogue
#pragma unroll
  for (int ni = 0; ni < 4; ni++) {
    const int col = n0 + wn * 64 + ni * 16 + r16;
    const float bvc = bias[col];
#pragma unroll
    for (int mi = 0; mi < 8; mi++) {
      const int row = m0 + wm * 128 + mi * 16 + quad * 4;
#pragma unroll
      for (int r = 0; r < 4; r++) {
        float v = acc[mi][ni][r] + bvc;
        size_t idx = (size_t)(row + r) * ldob + col;
        if (EPI == EPI_GELU) {
          float x = v;
          float y = 0.7978845608028654f * (x + 0.044715f * x * x * x);
          float e = exp2f(-2.8853900817779268f * y);  // exp(-2y)
          OB[idx] = f2b(x * __builtin_amdgcn_rcpf(1.0f + e));
        } else {  // EPI_MULG
          float g = b2f(G[idx]);
          OB[idx] = f2b(v * g);
        }
      }
    }
  }
}

// ---------------- flash attention ----------------
// qkv: [token][4096] (q cols 0..2047, k cols 2048..4095), vt: [ch 2048][token 4096]
// grid: (S/64, NH, B), block 256 (4 waves), each wave owns 16 q rows.
__global__ __launch_bounds__(256) void attn_kernel(const ushort* __restrict__ qkv,
                                                   const ushort* __restrict__ vt,
                                                   ushort* __restrict__ out) {
  constexpr int S = 2048;
  __shared__ alignas(16) ushort Ks[8192];  // 16 frags (nt*4+kk) * 64 lanes * 8
  __shared__ alignas(16) ushort Vs[8192];  // 16 frags (dt*2+kk2) * 64 lanes * 8
  __shared__ alignas(16) ushort Ps[4096];  // swizzled 64x64
  const int b = blockIdx.z, h = blockIdx.y, q0 = blockIdx.x * 64;
  const int tid = threadIdx.x, w = tid >> 6, L = tid & 63;
  const int r16 = L & 15, quad = L >> 4;

  bf16x8 aq[4];
  {
    const ushort* qb = qkv + (size_t)(b * S + q0 + w * 16 + r16) * 4096 + h * 128 + quad * 8;
#pragma unroll
    for (int kk = 0; kk < 4; kk++) aq[kk] = *(const bf16x8*)(qb + kk * 32);
  }

  const ushort* kb[4];
  const ushort* vb[4];
  ushort* kl[4];
  ushort* vl[4];
#pragma unroll
  for (int i = 0; i < 4; i++) {
    const int f = w * 4 + i;
    const int nt = f >> 2, kk = f & 3;
    kb[i] = qkv + (size_t)(b * S + nt * 16 + r16) * 4096 + 2048 + h * 128 + kk * 32 + quad * 8;
    kl[i] = &Ks[f * 512];
    const int dt = f >> 1, kk2 = f & 1;
    vb[i] = vt + (size_t)(h * 128 + dt * 16 + r16) * 4096 + b * S + kk2 * 32 + quad * 8;
    vl[i] = &Vs[f * 512];
  }

  float m_i[4] = {-1e30f, -1e30f, -1e30f, -1e30f};
  float l_i[4] = {0.f, 0.f, 0.f, 0.f};
  f32x4 o[8] = {};
  const float cl = 0.08838834764831845f * 1.4426950408889634f;

  for (int kt = 0; kt < 32; kt++) {
    const int k0 = kt * 64;
    __syncthreads();
#pragma unroll
    for (int i = 0; i < 4; i++) {
      async_cp16(kb[i] + (size_t)k0 * 4096, kl[i]);
      async_cp16(vb[i] + k0, vl[i]);
    }
    __syncthreads();

    f32x4 sf[4];
#pragma unroll
    for (int nt = 0; nt < 4; nt++) {
      f32x4 a = {};
#pragma unroll
      for (int kk = 0; kk < 4; kk++) {
        bf16x8 bk = *(const bf16x8*)&Ks[((nt * 4 + kk) * 64 + L) * 8];
        a = __builtin_amdgcn_mfma_f32_16x16x32_bf16(aq[kk], bk, a, 0, 0, 0);
      }
      sf[nt] = a;
    }

    float al[4];
    float pv[4][4];
#pragma unroll
    for (int r = 0; r < 4; r++) {
      float mx = fmaxf(fmaxf(sf[0][r], sf[1][r]), fmaxf(sf[2][r], sf[3][r]));
      mx = fmaxf(mx, __shfl_xor(mx, 1));
      mx = fmaxf(mx, __shfl_xor(mx, 2));
      mx = fmaxf(mx, __shfl_xor(mx, 4));
      mx = fmaxf(mx, __shfl_xor(mx, 8));
      float mnew = fmaxf(m_i[r], mx);
      al[r] = exp2f((m_i[r] - mnew) * cl);
      m_i[r] = mnew;
      float rs = 0.f;
#pragma unroll
      for (int nt = 0; nt < 4; nt++) {
        float p = exp2f((sf[nt][r] - mnew) * cl);
        pv[nt][r] = p;
        rs += p;
      }
      rs += __shfl_xor(rs, 1);
      rs += __shfl_xor(rs, 2);
      rs += __shfl_xor(rs, 4);
      rs += __shfl_xor(rs, 8);
      l_i[r] = l_i[r] * al[r] + rs;
    }

#pragma unroll
    for (int nt = 0; nt < 4; nt++)
#pragma unroll
      for (int r = 0; r < 4; r++) {
        const int q = quad * 4 + r;
        const int addr =
            (w * 16 + q) * 64 + (((nt * 2 + (r16 >> 3)) ^ (q & 7)) << 3) + (r16 & 7);
        Ps[addr] = f2b(pv[nt][r]);
      }

#pragma unroll
    for (int dt = 0; dt < 8; dt++) {
      f32x4 t = o[dt];
      t[0] *= al[0]; t[1] *= al[1]; t[2] *= al[2]; t[3] *= al[3];
      o[dt] = t;
    }
    __syncthreads();

    bf16x8 ap[2];
#pragma unroll
    for (int kk2 = 0; kk2 < 2; kk2++)
      ap[kk2] = *(const bf16x8*)
          &Ps[(w * 16 + r16) * 64 + (((kk2 * 4 + quad) ^ (r16 & 7)) << 3)];
#pragma unroll
    for (int dt = 0; dt < 8; dt++) {
#pragma unroll
      for (int kk2 = 0; kk2 < 2; kk2++) {
        bf16x8 bv = *(const bf16x8*)&Vs[((dt * 2 + kk2) * 64 + L) * 8];
        o[dt] = __builtin_amdgcn_mfma_f32_16x16x32_bf16(ap[kk2], bv, o[dt], 0, 0, 0);
      }
    }
  }

  float linv[4];
#pragma unroll
  for (int r = 0; r < 4; r++) linv[r] = 1.0f / l_i[r];
#pragma unroll
  for (int dt = 0; dt < 8; dt++)
#pragma unroll
    for (int r = 0; r < 4; r++) {
      int row = q0 + w * 16 + quad * 4 + r;
      out[(size_t)(b * S + row) * 2048 + h * 128 + dt * 16 + r16] = f2b(o[dt][r] * linv[r]);
    }
}

// ---------------- launch ----------------

extern "C" void kernel_launch(void* const* d_in, const int* in_sizes, int n_in,
                              void* d_out, int out_size, void* d_ws, size_t ws_size,
                              hipStream_t stream) {
  const float* hidden = (const float*)d_in[0];
  const float* temb = (const float*)d_in[1];
  const float* Wq = (const float*)d_in[2];
  const float* bq = (const float*)d_in[3];
  const float* Wk = (const float*)d_in[4];
  const float* bk = (const float*)d_in[5];
  const float* Wv = (const float*)d_in[6];
  const float* bv = (const float*)d_in[7];
  const float* Wo = (const float*)d_in[8];
  const float* bo = (const float*)d_in[9];
  const float* Wff = (const float*)d_in[10];
  const float* bff = (const float*)d_in[11];
  const float* Wfo = (const float*)d_in[12];
  const float* bfo = (const float*)d_in[13];
  const float* sst = (const float*)d_in[14];
  float* out = (float*)d_out;

  char* ws = (char*)d_ws;
  size_t off = 0;
  auto alloc = [&](size_t bytes) {
    void* p = ws + off;
    off += (bytes + 255) & ~(size_t)255;
    return p;
  };
  ushort* wWq = (ushort*)alloc(4194304ull * 2);
  ushort* wWk = (ushort*)alloc(4194304ull * 2);
  ushort* wWv = (ushort*)alloc(4194304ull * 2);
  ushort* wWo = (ushort*)alloc(4194304ull * 2);
  ushort* wWff = (ushort*)alloc(33554432ull * 2);
  ushort* wWfo = (ushort*)alloc(16777216ull * 2);
  float* modsb = (float*)alloc(24576ull * 4);
  ushort* normb = (ushort*)alloc(8388608ull * 2);     // norm1, later norm2
  ushort* qkvb = (ushort*)alloc(4096ull * 4096 * 2);  // q|k  [token][4096]
  ushort* vtb = (ushort*)alloc(2048ull * 4096 * 2);   // V^T [ch][token]
  ushort* attnb = (ushort*)alloc(8388608ull * 2);
  ushort* ffgb = (ushort*)alloc(33554432ull * 2);
  ushort* gb = qkvb;  // gelu output aliases qkvb+vtb+attnb (64 MB, all dead by then)

  const int T = 256;
  f32_to_bf16<<<1024, T, 0, stream>>>(Wq, wWq, 1048576);
  f32_to_bf16<<<1024, T, 0, stream>>>(Wk, wWk, 1048576);
  f32_to_bf16<<<1024, T, 0, stream>>>(Wv, wWv, 1048576);
  f32_to_bf16<<<1024, T, 0, stream>>>(Wo, wWo, 1048576);
  f32_to_bf16<<<2048, T, 0, stream>>>(Wff, wWff, 8388608);
  f32_to_bf16<<<2048, T, 0, stream>>>(Wfo, wWfo, 4194304);
  mods_k<<<96, T, 0, stream>>>(sst, temb, modsb);
  norm1_k<<<8192, T, 0, stream>>>(hidden, modsb, normb);

  dim3 gq(16, 32);
  gemm_bt<EPI_QKV><<<gq, T, 0, stream>>>(normb, 2048, wWq, 2048, bq, 2048, nullptr, qkvb,
                                         4096, 0, nullptr, nullptr, nullptr);
  gemm_bt<EPI_QKV><<<gq, T, 0, stream>>>(normb, 2048, wWk, 2048, bk, 2048, nullptr, qkvb,
                                         4096, 2048, nullptr, nullptr, nullptr);
  // V^T = Wv * norm1^T  (swapped operands -> output [ch][token])
  gemm_bt<EPI_VT><<<dim3(32, 16), T, 0, stream>>>(wWv, 2048, normb, 2048, bv, 2048, nullptr,
                                                  vtb, 4096, 0, nullptr, nullptr, nullptr);
  qk_ln<<<32768, T, 0, stream>>>(qkvb);
  attn_kernel<<<dim3(32, 16, 2), T, 0, stream>>>(qkvb, vtb, attnb);
  gemm_bt<EPI_ATTNOUT><<<gq, T, 0, stream>>>(attnb, 2048, wWo, 2048, bo, 2048, out, normb,
                                             2048, 0, hidden, modsb, nullptr);
  // FF-up GEMMs on the 256x256 deep-pipelined path (N=8192 -> 512 blocks, 2/CU rounds)
  dim3 g256(32, 16);
  gemm256<EPI_GELU><<<g256, 512, 0, stream>>>(normb, 2048, wWff + (size_t)8192 * 2048, 2048,
                                              bff + 8192, 2048, gb, 8192, nullptr);
  gemm256<EPI_MULG><<<g256, 512, 0, stream>>>(normb, 2048, wWff, 2048, bff, 2048, ffgb,
                                              8192, gb);
  gemm_bt<EPI_FINAL><<<gq, T, 0, stream>>>(ffgb, 8192, wWfo, 8192, bfo, 8192, out, nullptr,
                                           0, 0, nullptr, modsb, nullptr);
}

// Round 2
// 1267.691 us; speedup vs baseline: 1.3176x; 1.1797x over previous
//
#include <hip/hip_runtime.h>
#include <stdint.h>

#define DEVI __device__ __forceinline__

typedef float f32x4 __attribute__((ext_vector_type(4)));
typedef __bf16 bf16x8 __attribute__((ext_vector_type(8)));

DEVI ushort f2b(float f) {
  uint32_t x = __float_as_uint(f);
  uint32_t r = (x + 0x7fffu + ((x >> 16) & 1u)) >> 16;
  return (ushort)r;
}
DEVI float b2f(ushort u) { return __uint_as_float(((uint32_t)u) << 16); }

DEVI void async_cp16(const void* g, void* l) {
  __builtin_amdgcn_global_load_lds(
      (__attribute__((address_space(1))) void*)(uintptr_t)(g),
      (__attribute__((address_space(3))) void*)(uintptr_t)(l), 16, 0, 0);
}

DEVI f32x4 MF(bf16x8 a, bf16x8 b, f32x4 c) {
  return __builtin_amdgcn_mfma_f32_16x16x32_bf16(a, b, c, 0, 0, 0);
}

#define MFENCE asm volatile("" ::: "memory")
#define BARRIER                       \
  do {                                \
    MFENCE;                           \
    __builtin_amdgcn_s_barrier();     \
    MFENCE;                           \
  } while (0)

// ---------------- elementwise helpers ----------------

__global__ void f32_to_bf16(const float* __restrict__ s, ushort* __restrict__ d, int n4) {
  int stride = gridDim.x * blockDim.x;
  for (int i = blockIdx.x * blockDim.x + threadIdx.x; i < n4; i += stride) {
    float4 v = ((const float4*)s)[i];
    ushort4 o;
    o.x = f2b(v.x); o.y = f2b(v.y); o.z = f2b(v.z); o.w = f2b(v.w);
    ((ushort4*)d)[i] = o;
  }
}

// mods[b,i,h] = sst[i,h] + temb[b,h];  n = 2*6*2048 = 24576
__global__ void mods_k(const float* __restrict__ sst, const float* __restrict__ temb,
                       float* __restrict__ mods) {
  int i = blockIdx.x * blockDim.x + threadIdx.x;
  int b = i / 12288;
  int rem = i - b * 12288;
  mods[i] = sst[rem] + temb[b * 2048 + (rem & 2047)];
}

// norm1 = bf16(hidden*(1+scale_msa)+shift_msa); one thread per 4 elems
__global__ void norm1_k(const float* __restrict__ hid, const float* __restrict__ mods,
                        ushort* __restrict__ out) {
  int i = blockIdx.x * blockDim.x + threadIdx.x;  // < 2097152
  int e = i * 4;
  int b = e >> 22;
  int h = e & 2047;
  float4 v = ((const float4*)hid)[i];
  const float* mb = mods + b * 12288;
  float4 sc = *(const float4*)(mb + 2048 + h);
  float4 sh = *(const float4*)(mb + h);
  ushort4 o;
  o.x = f2b(v.x * (1.f + sc.x) + sh.x);
  o.y = f2b(v.y * (1.f + sc.y) + sh.y);
  o.z = f2b(v.z * (1.f + sc.z) + sh.z);
  o.w = f2b(v.w * (1.f + sc.w) + sh.w);
  ((ushort4*)out)[i] = o;
}

// per-head layernorm on q and k halves of qkv (layout [token][4096]), in place.
__global__ __launch_bounds__(256) void qk_ln(ushort* __restrict__ qkv) {
  const int rid = blockIdx.x * 4 + (threadIdx.x >> 6);
  const int L = threadIdx.x & 63;
  const int half = rid >> 16;        // 0: q, 1: k (65536 rows each)
  const int r2 = rid & 65535;
  const int bs = r2 >> 4, head = r2 & 15;
  ushort* p = qkv + (size_t)bs * 4096 + half * 2048 + head * 128 + L * 2;
  uint32_t u = *(const uint32_t*)p;
  float e0 = b2f((ushort)(u & 0xffff));
  float e1 = b2f((ushort)(u >> 16));
  float s = e0 + e1;
#pragma unroll
  for (int d = 1; d < 64; d <<= 1) s += __shfl_xor(s, d);
  float mu = s * (1.0f / 128.0f);
  float d0 = e0 - mu, d1 = e1 - mu;
  float vq = d0 * d0 + d1 * d1;
#pragma unroll
  for (int d = 1; d < 64; d <<= 1) vq += __shfl_xor(vq, d);
  float rstd = rsqrtf(vq * (1.0f / 128.0f) + 1e-5f);
  uint32_t ou = (uint32_t)f2b(d0 * rstd) | ((uint32_t)f2b(d1 * rstd) << 16);
  *(uint32_t*)p = ou;
}

enum { EPI_QKV = 0, EPI_ATTNOUT = 1, EPI_GELU = 2, EPI_MULG = 3, EPI_FINAL = 4, EPI_VT = 5 };

// ---------------- GEMM 128x256, 8-wave, deep pipeline ----------------
// BM=128, BN=256, BK=64, 512 threads (8 waves 2Mx4N), wave output 64x64.
// LDS 96 KiB: per dbuf { A: [kk 2][rg 8][512], B: at +8192 [kk 2][rg 16][512] }.
// Swizzle: phys 16B-slot s of row r holds k-slot s^((r>>1)&3); applied on the global
// SOURCE addr (global_load_lds dest linear) and on ds_read addr.
// 2 phases/K-tile: {8 ds_read_b128; issue 3 gload_lds (next tile); barrier;
// setprio 16 MFMA; vmcnt(3); barrier}. Steady state 3-6 loads in flight, never 0.

template <int EPI>
__global__ __launch_bounds__(512, 2) void gemm128(
    const ushort* __restrict__ A, int lda,
    const ushort* __restrict__ W, int ldw,
    const float* __restrict__ bias, int K,
    float* __restrict__ OF,
    ushort* __restrict__ OB, int ldob, int col0,
    const float* __restrict__ R0,
    const float* __restrict__ mods) {
  __shared__ alignas(16) ushort lds[49152];
  const int tid = threadIdx.x;
  const int w = tid >> 6, L = tid & 63;
  const int r16 = L & 15, quad = L >> 4;
  const int wm = w >> 2, wn = w & 3;

  // T1: bijective XCD swizzle (all grids are multiples of 8)
  const int nwg = gridDim.x * gridDim.y;
  const int id0 = blockIdx.y * gridDim.x + blockIdx.x;
  const int swz = (id0 & 7) * (nwg >> 3) + (id0 >> 3);
  const int m0 = (swz / gridDim.x) * 128, n0 = (swz % gridDim.x) * 256;

  const int sA = quad ^ ((r16 >> 1) & 3);           // read k-slot
  const int kswz = 8 * ((L & 3) ^ ((L >> 3) & 3));  // stage-source k-offset

  const int aoff = wm * 2048 + r16 * 32 + 8 * sA;           // + kk*4096 + mi*512
  const int boff = 8192 + wn * 2048 + r16 * 32 + 8 * sA;    // + kk*8192 + ni*512

  // staging: 0=A.kk0, 1=B.kk0.lo, 2=B.kk0.hi, 3=A.kk1, 4=B.kk1.lo, 5=B.kk1.hi
  const ushort* src[6];
  int ldst[6];
#pragma unroll
  for (int i = 0; i < 6; i++) {
    const int kk = i / 3, s = i % 3;  // s: 0=A, 1=B lo-half, 2=B hi-half
    const int rg = (s == 2) ? (8 + w) : w;
    const int grow = rg * 16 + (L >> 2);
    src[i] = (s ? W + (size_t)(n0 + grow) * ldw : A + (size_t)(m0 + grow) * lda) +
             kk * 32 + kswz;
    ldst[i] = s ? (8192 + kk * 8192 + rg * 512) : (kk * 4096 + w * 512);
  }

  f32x4 acc[4][4] = {};
  const int NT = K >> 6;

  // prologue: tile 0 -> buf 0, one-time full drain
#pragma unroll
  for (int i = 0; i < 6; i++) {
    async_cp16(src[i], &lds[ldst[i]]);
    src[i] += 64;
  }
  asm volatile("s_waitcnt vmcnt(0)" ::: "memory");
  __builtin_amdgcn_s_barrier();
  MFENCE;

  for (int t = 0; t < NT - 1; ++t) {
    const int cb = (t & 1) * 24576, nb = cb ^ 24576;
    const ushort* Ab = &lds[cb + aoff];
    const ushort* Bb = &lds[cb + boff];
    bf16x8 af[4], bq[4];

    // ---- P0: kk0
#pragma unroll
    for (int mi = 0; mi < 4; mi++) af[mi] = *(const bf16x8*)(Ab + mi * 512);
#pragma unroll
    for (int ni = 0; ni < 4; ni++) bq[ni] = *(const bf16x8*)(Bb + ni * 512);
    async_cp16(src[0], &lds[nb + ldst[0]]); src[0] += 64;
    async_cp16(src[1], &lds[nb + ldst[1]]); src[1] += 64;
    async_cp16(src[2], &lds[nb + ldst[2]]); src[2] += 64;
    BARRIER;
    __builtin_amdgcn_s_setprio(1);
#pragma unroll
    for (int mi = 0; mi < 4; mi++)
#pragma unroll
      for (int ni = 0; ni < 4; ni++) acc[mi][ni] = MF(af[mi], bq[ni], acc[mi][ni]);
    __builtin_amdgcn_s_setprio(0);
    // drains tile-t kk1 (oldest 3); leaves t+1 kk0 in flight
    asm volatile("s_waitcnt vmcnt(3)" ::: "memory");
    __builtin_amdgcn_s_barrier();
    MFENCE;

    // ---- P1: kk1
#pragma unroll
    for (int mi = 0; mi < 4; mi++) af[mi] = *(const bf16x8*)(Ab + 4096 + mi * 512);
#pragma unroll
    for (int ni = 0; ni < 4; ni++) bq[ni] = *(const bf16x8*)(Bb + 8192 + ni * 512);
    async_cp16(src[3], &lds[nb + ldst[3]]); src[3] += 64;
    async_cp16(src[4], &lds[nb + ldst[4]]); src[4] += 64;
    async_cp16(src[5], &lds[nb + ldst[5]]); src[5] += 64;
    BARRIER;
    __builtin_amdgcn_s_setprio(1);
#pragma unroll
    for (int mi = 0; mi < 4; mi++)
#pragma unroll
      for (int ni = 0; ni < 4; ni++) acc[mi][ni] = MF(af[mi], bq[ni], acc[mi][ni]);
    __builtin_amdgcn_s_setprio(0);
    // drains t+1 kk0 (oldest 3); leaves t+1 kk1 in flight
    asm volatile("s_waitcnt vmcnt(3)" ::: "memory");
    __builtin_amdgcn_s_barrier();
    MFENCE;
  }

  // peeled last tile (no staging)
  {
    const int cb = ((NT - 1) & 1) * 24576;
    const ushort* Ab = &lds[cb + aoff];
    const ushort* Bb = &lds[cb + boff];
    bf16x8 af[4], bq[4];
#pragma unroll
    for (int mi = 0; mi < 4; mi++) af[mi] = *(const bf16x8*)(Ab + mi * 512);
#pragma unroll
    for (int ni = 0; ni < 4; ni++) bq[ni] = *(const bf16x8*)(Bb + ni * 512);
#pragma unroll
    for (int mi = 0; mi < 4; mi++)
#pragma unroll
      for (int ni = 0; ni < 4; ni++) acc[mi][ni] = MF(af[mi], bq[ni], acc[mi][ni]);
    asm volatile("s_waitcnt vmcnt(0)" ::: "memory");
    __builtin_amdgcn_s_barrier();
    MFENCE;
#pragma unroll
    for (int mi = 0; mi < 4; mi++) af[mi] = *(const bf16x8*)(Ab + 4096 + mi * 512);
#pragma unroll
    for (int ni = 0; ni < 4; ni++) bq[ni] = *(const bf16x8*)(Bb + 8192 + ni * 512);
#pragma unroll
    for (int mi = 0; mi < 4; mi++)
#pragma unroll
      for (int ni = 0; ni < 4; ni++) acc[mi][ni] = MF(af[mi], bq[ni], acc[mi][ni]);
  }

  // epilogue
#pragma unroll
  for (int ni = 0; ni < 4; ni++) {
    const int col = n0 + wn * 64 + ni * 16 + r16;
    const float bvc = bias[(EPI == EPI_VT) ? 0 : col];
#pragma unroll
    for (int mi = 0; mi < 4; mi++) {
      const int row0 = m0 + wm * 64 + mi * 16 + quad * 4;
#pragma unroll
      for (int r = 0; r < 4; r++) {
        const int row = row0 + r;
        float v = acc[mi][ni][r] + ((EPI == EPI_VT) ? bias[row] : bvc);
        if (EPI == EPI_QKV) {
          OB[(size_t)row * ldob + col0 + col] = f2b(v);
        } else if (EPI == EPI_VT) {
          OB[(size_t)row * ldob + col] = f2b(v);
        } else if (EPI == EPI_ATTNOUT) {
          const int b = row >> 11;
          const float* mb = mods + b * 12288;
          float o = R0[(size_t)row * 2048 + col] + mb[2 * 2048 + col] * v;
          OF[(size_t)row * 2048 + col] = o;
          OB[(size_t)row * 2048 + col] =
              f2b(o * (1.0f + mb[4 * 2048 + col]) + mb[3 * 2048 + col]);
        } else {  // EPI_FINAL
          const int b = row >> 11;
          const float* mb = mods + b * 12288;
          size_t idx = (size_t)row * 2048 + col;
          OF[idx] = OF[idx] + mb[5 * 2048 + col] * v;
        }
      }
    }
  }
}

// ---------------- GEMM 256x256, 8-wave, deep pipeline (FF-up shapes) ----------------

template <int EPI>
__global__ __launch_bounds__(512, 2) void gemm256(
    const ushort* __restrict__ A, int lda,
    const ushort* __restrict__ W, int ldw,
    const float* __restrict__ bias, int K,
    ushort* __restrict__ OB, int ldob,
    const ushort* __restrict__ G) {
  __shared__ alignas(16) ushort lds[65536];
  const int tid = threadIdx.x;
  const int w = tid >> 6, L = tid & 63;
  const int r16 = L & 15, quad = L >> 4;
  const int wm = w >> 2, wn = w & 3;

  // T1: bijective XCD swizzle
  const int nwg = gridDim.x * gridDim.y;
  const int id0 = blockIdx.y * gridDim.x + blockIdx.x;
  const int swz = (id0 & 7) * (nwg >> 3) + (id0 >> 3);
  const int m0 = (swz / gridDim.x) * 256, n0 = (swz % gridDim.x) * 256;

  const int sA = quad ^ ((r16 >> 1) & 3);
  const int kswz = 8 * ((L & 3) ^ ((L >> 3) & 3));

  const int aoff = wm * 8192 + r16 * 32 + 8 * sA;
  const int boff = 16384 + (wn >> 1) * 8192 + (wn & 1) * 2048 + r16 * 32 + 8 * sA;

  const ushort* src[8];
  int ldst[8];
#pragma unroll
  for (int i = 0; i < 8; i++) {
    const int mat = (i >> 1) & 1, kk = i >> 2;
    const int j = w * 2 + (i & 1), half = j >> 3, rg = j & 7;
    const int grow = half * 128 + rg * 16 + (L >> 2);
    src[i] = (mat ? W + (size_t)(n0 + grow) * ldw : A + (size_t)(m0 + grow) * lda) +
             kk * 32 + kswz;
    ldst[i] = mat * 16384 + half * 8192 + kk * 4096 + rg * 512;
  }

  f32x4 acc[8][4] = {};
  const int NT = K >> 6;

#pragma unroll
  for (int i = 0; i < 8; i++) {
    async_cp16(src[i], &lds[ldst[i]]);
    src[i] += 64;
  }
  asm volatile("s_waitcnt vmcnt(0)" ::: "memory");
  __builtin_amdgcn_s_barrier();
  MFENCE;

  for (int t = 0; t < NT - 1; ++t) {
    const int cb = (t & 1) << 15, nb = cb ^ 32768;
    const ushort* Ab = &lds[cb + aoff];
    const ushort* Bb = &lds[cb + boff];
    bf16x8 af[8], bq[2];

    // ---- P0: kk0, ni 0-1
#pragma unroll
    for (int mi = 0; mi < 8; mi++) af[mi] = *(const bf16x8*)(Ab + mi * 512);
    bq[0] = *(const bf16x8*)(Bb);
    bq[1] = *(const bf16x8*)(Bb + 512);
    async_cp16(src[0], &lds[nb + ldst[0]]); src[0] += 64;
    async_cp16(src[1], &lds[nb + ldst[1]]); src[1] += 64;
    BARRIER;
    __builtin_amdgcn_s_setprio(1);
#pragma unroll
    for (int mi = 0; mi < 8; mi++) {
      acc[mi][0] = MF(af[mi], bq[0], acc[mi][0]);
      acc[mi][1] = MF(af[mi], bq[1], acc[mi][1]);
    }
    __builtin_amdgcn_s_setprio(0);
    BARRIER;

    // ---- P1: kk0, ni 2-3
    bq[0] = *(const bf16x8*)(Bb + 1024);
    bq[1] = *(const bf16x8*)(Bb + 1536);
    async_cp16(src[2], &lds[nb + ldst[2]]); src[2] += 64;
    async_cp16(src[3], &lds[nb + ldst[3]]); src[3] += 64;
    BARRIER;
    __builtin_amdgcn_s_setprio(1);
#pragma unroll
    for (int mi = 0; mi < 8; mi++) {
      acc[mi][2] = MF(af[mi], bq[0], acc[mi][2]);
      acc[mi][3] = MF(af[mi], bq[1], acc[mi][3]);
    }
    __builtin_amdgcn_s_setprio(0);
    asm volatile("s_waitcnt vmcnt(4)" ::: "memory");
    __builtin_amdgcn_s_barrier();
    MFENCE;

    // ---- P2: kk1, ni 0-1
#pragma unroll
    for (int mi = 0; mi < 8; mi++) af[mi] = *(const bf16x8*)(Ab + 4096 + mi * 512);
    bq[0] = *(const bf16x8*)(Bb + 4096);
    bq[1] = *(const bf16x8*)(Bb + 4096 + 512);
    async_cp16(src[4], &lds[nb + ldst[4]]); src[4] += 64;
    async_cp16(src[5], &lds[nb + ldst[5]]); src[5] += 64;
    BARRIER;
    __builtin_amdgcn_s_setprio(1);
#pragma unroll
    for (int mi = 0; mi < 8; mi++) {
      acc[mi][0] = MF(af[mi], bq[0], acc[mi][0]);
      acc[mi][1] = MF(af[mi], bq[1], acc[mi][1]);
    }
    __builtin_amdgcn_s_setprio(0);
    BARRIER;

    // ---- P3: kk1, ni 2-3
    bq[0] = *(const bf16x8*)(Bb + 4096 + 1024);
    bq[1] = *(const bf16x8*)(Bb + 4096 + 1536);
    async_cp16(src[6], &lds[nb + ldst[6]]); src[6] += 64;
    async_cp16(src[7], &lds[nb + ldst[7]]); src[7] += 64;
    BARRIER;
    __builtin_amdgcn_s_setprio(1);
#pragma unroll
    for (int mi = 0; mi < 8; mi++) {
      acc[mi][2] = MF(af[mi], bq[0], acc[mi][2]);
      acc[mi][3] = MF(af[mi], bq[1], acc[mi][3]);
    }
    __builtin_amdgcn_s_setprio(0);
    asm volatile("s_waitcnt vmcnt(4)" ::: "memory");
    __builtin_amdgcn_s_barrier();
    MFENCE;
  }

  // peeled last tile
  {
    const int cb = ((NT - 1) & 1) << 15;
    const ushort* Ab = &lds[cb + aoff];
    const ushort* Bb = &lds[cb + boff];
    bf16x8 af[8], bq[4];
#pragma unroll
    for (int mi = 0; mi < 8; mi++) af[mi] = *(const bf16x8*)(Ab + mi * 512);
#pragma unroll
    for (int ni = 0; ni < 4; ni++) bq[ni] = *(const bf16x8*)(Bb + ni * 512);
#pragma unroll
    for (int mi = 0; mi < 8; mi++)
#pragma unroll
      for (int ni = 0; ni < 4; ni++) acc[mi][ni] = MF(af[mi], bq[ni], acc[mi][ni]);
    asm volatile("s_waitcnt vmcnt(0)" ::: "memory");
    __builtin_amdgcn_s_barrier();
    MFENCE;
#pragma unroll
    for (int mi = 0; mi < 8; mi++) af[mi] = *(const bf16x8*)(Ab + 4096 + mi * 512);
#pragma unroll
    for (int ni = 0; ni < 4; ni++) bq[ni] = *(const bf16x8*)(Bb + 4096 + ni * 512);
#pragma unroll
    for (int mi = 0; mi < 8; mi++)
#pragma unroll
      for (int ni = 0; ni < 4; ni++) acc[mi][ni] = MF(af[mi], bq[ni], acc[mi][ni]);
  }

  // epilogue
#pragma unroll
  for (int ni = 0; ni < 4; ni++) {
    const int col = n0 + wn * 64 + ni * 16 + r16;
    const float bvc = bias[col];
#pragma unroll
    for (int mi = 0; mi < 8; mi++) {
      const int row = m0 + wm * 128 + mi * 16 + quad * 4;
#pragma unroll
      for (int r = 0; r < 4; r++) {
        float v = acc[mi][ni][r] + bvc;
        size_t idx = (size_t)(row + r) * ldob + col;
        if (EPI == EPI_GELU) {
          float x = v;
          float y = 0.7978845608028654f * (x + 0.044715f * x * x * x);
          float e = exp2f(-2.8853900817779268f * y);  // exp(-2y)
          OB[idx] = f2b(x * __builtin_amdgcn_rcpf(1.0f + e));
        } else {  // EPI_MULG
          float g = b2f(G[idx]);
          OB[idx] = f2b(v * g);
        }
      }
    }
  }
}

// ---------------- flash attention ----------------
// qkv: [token][4096] (q cols 0..2047, k cols 2048..4095), vt: [ch 2048][token 4096]
// grid: (S/64, NH, B), block 256 (4 waves), each wave owns 16 q rows.
__global__ __launch_bounds__(256) void attn_kernel(const ushort* __restrict__ qkv,
                                                   const ushort* __restrict__ vt,
                                                   ushort* __restrict__ out) {
  constexpr int S = 2048;
  __shared__ alignas(16) ushort Ks[8192];  // 16 frags (nt*4+kk) * 64 lanes * 8
  __shared__ alignas(16) ushort Vs[8192];  // 16 frags (dt*2+kk2) * 64 lanes * 8
  __shared__ alignas(16) ushort Ps[4096];  // swizzled 64x64
  const int b = blockIdx.z, h = blockIdx.y, q0 = blockIdx.x * 64;
  const int tid = threadIdx.x, w = tid >> 6, L = tid & 63;
  const int r16 = L & 15, quad = L >> 4;

  bf16x8 aq[4];
  {
    const ushort* qb = qkv + (size_t)(b * S + q0 + w * 16 + r16) * 4096 + h * 128 + quad * 8;
#pragma unroll
    for (int kk = 0; kk < 4; kk++) aq[kk] = *(const bf16x8*)(qb + kk * 32);
  }

  const ushort* kb[4];
  const ushort* vb[4];
  ushort* kl[4];
  ushort* vl[4];
#pragma unroll
  for (int i = 0; i < 4; i++) {
    const int f = w * 4 + i;
    const int nt = f >> 2, kk = f & 3;
    kb[i] = qkv + (size_t)(b * S + nt * 16 + r16) * 4096 + 2048 + h * 128 + kk * 32 + quad * 8;
    kl[i] = &Ks[f * 512];
    const int dt = f >> 1, kk2 = f & 1;
    vb[i] = vt + (size_t)(h * 128 + dt * 16 + r16) * 4096 + b * S + kk2 * 32 + quad * 8;
    vl[i] = &Vs[f * 512];
  }

  float m_i[4] = {-1e30f, -1e30f, -1e30f, -1e30f};
  float l_i[4] = {0.f, 0.f, 0.f, 0.f};
  f32x4 o[8] = {};
  const float cl = 0.08838834764831845f * 1.4426950408889634f;

  for (int kt = 0; kt < 32; kt++) {
    const int k0 = kt * 64;
    __syncthreads();
#pragma unroll
    for (int i = 0; i < 4; i++) {
      async_cp16(kb[i] + (size_t)k0 * 4096, kl[i]);
      async_cp16(vb[i] + k0, vl[i]);
    }
    __syncthreads();

    f32x4 sf[4];
#pragma unroll
    for (int nt = 0; nt < 4; nt++) {
      f32x4 a = {};
#pragma unroll
      for (int kk = 0; kk < 4; kk++) {
        bf16x8 bk = *(const bf16x8*)&Ks[((nt * 4 + kk) * 64 + L) * 8];
        a = __builtin_amdgcn_mfma_f32_16x16x32_bf16(aq[kk], bk, a, 0, 0, 0);
      }
      sf[nt] = a;
    }

    float al[4];
    float pv[4][4];
#pragma unroll
    for (int r = 0; r < 4; r++) {
      float mx = fmaxf(fmaxf(sf[0][r], sf[1][r]), fmaxf(sf[2][r], sf[3][r]));
      mx = fmaxf(mx, __shfl_xor(mx, 1));
      mx = fmaxf(mx, __shfl_xor(mx, 2));
      mx = fmaxf(mx, __shfl_xor(mx, 4));
      mx = fmaxf(mx, __shfl_xor(mx, 8));
      float mnew = fmaxf(m_i[r], mx);
      al[r] = exp2f((m_i[r] - mnew) * cl);
      m_i[r] = mnew;
      float rs = 0.f;
#pragma unroll
      for (int nt = 0; nt < 4; nt++) {
        float p = exp2f((sf[nt][r] - mnew) * cl);
        pv[nt][r] = p;
        rs += p;
      }
      rs += __shfl_xor(rs, 1);
      rs += __shfl_xor(rs, 2);
      rs += __shfl_xor(rs, 4);
      rs += __shfl_xor(rs, 8);
      l_i[r] = l_i[r] * al[r] + rs;
    }

#pragma unroll
    for (int nt = 0; nt < 4; nt++)
#pragma unroll
      for (int r = 0; r < 4; r++) {
        const int q = quad * 4 + r;
        const int addr =
            (w * 16 + q) * 64 + (((nt * 2 + (r16 >> 3)) ^ (q & 7)) << 3) + (r16 & 7);
        Ps[addr] = f2b(pv[nt][r]);
      }

#pragma unroll
    for (int dt = 0; dt < 8; dt++) {
      f32x4 t = o[dt];
      t[0] *= al[0]; t[1] *= al[1]; t[2] *= al[2]; t[3] *= al[3];
      o[dt] = t;
    }
    __syncthreads();

    bf16x8 ap[2];
#pragma unroll
    for (int kk2 = 0; kk2 < 2; kk2++)
      ap[kk2] = *(const bf16x8*)
          &Ps[(w * 16 + r16) * 64 + (((kk2 * 4 + quad) ^ (r16 & 7)) << 3)];
#pragma unroll
    for (int dt = 0; dt < 8; dt++) {
#pragma unroll
      for (int kk2 = 0; kk2 < 2; kk2++) {
        bf16x8 bv = *(const bf16x8*)&Vs[((dt * 2 + kk2) * 64 + L) * 8];
        o[dt] = __builtin_amdgcn_mfma_f32_16x16x32_bf16(ap[kk2], bv, o[dt], 0, 0, 0);
      }
    }
  }

  float linv[4];
#pragma unroll
  for (int r = 0; r < 4; r++) linv[r] = 1.0f / l_i[r];
#pragma unroll
  for (int dt = 0; dt < 8; dt++)
#pragma unroll
    for (int r = 0; r < 4; r++) {
      int row = q0 + w * 16 + quad * 4 + r;
      out[(size_t)(b * S + row) * 2048 + h * 128 + dt * 16 + r16] = f2b(o[dt][r] * linv[r]);
    }
}

// ---------------- launch ----------------

extern "C" void kernel_launch(void* const* d_in, const int* in_sizes, int n_in,
                              void* d_out, int out_size, void* d_ws, size_t ws_size,
                              hipStream_t stream) {
  const float* hidden = (const float*)d_in[0];
  const float* temb = (const float*)d_in[1];
  const float* Wq = (const float*)d_in[2];
  const float* bq = (const float*)d_in[3];
  const float* Wk = (const float*)d_in[4];
  const float* bk = (const float*)d_in[5];
  const float* Wv = (const float*)d_in[6];
  const float* bv = (const float*)d_in[7];
  const float* Wo = (const float*)d_in[8];
  const float* bo = (const float*)d_in[9];
  const float* Wff = (const float*)d_in[10];
  const float* bff = (const float*)d_in[11];
  const float* Wfo = (const float*)d_in[12];
  const float* bfo = (const float*)d_in[13];
  const float* sst = (const float*)d_in[14];
  float* out = (float*)d_out;

  char* ws = (char*)d_ws;
  size_t off = 0;
  auto alloc = [&](size_t bytes) {
    void* p = ws + off;
    off += (bytes + 255) & ~(size_t)255;
    return p;
  };
  ushort* wWq = (ushort*)alloc(4194304ull * 2);
  ushort* wWk = (ushort*)alloc(4194304ull * 2);
  ushort* wWv = (ushort*)alloc(4194304ull * 2);
  ushort* wWo = (ushort*)alloc(4194304ull * 2);
  ushort* wWff = (ushort*)alloc(33554432ull * 2);
  ushort* wWfo = (ushort*)alloc(16777216ull * 2);
  float* modsb = (float*)alloc(24576ull * 4);
  ushort* normb = (ushort*)alloc(8388608ull * 2);     // norm1, later norm2
  ushort* qkvb = (ushort*)alloc(4096ull * 4096 * 2);  // q|k  [token][4096]
  ushort* vtb = (ushort*)alloc(2048ull * 4096 * 2);   // V^T [ch][token]
  ushort* attnb = (ushort*)alloc(8388608ull * 2);
  ushort* ffgb = (ushort*)alloc(33554432ull * 2);
  ushort* gb = qkvb;  // gelu output aliases qkvb+vtb+attnb (64 MB, all dead by then)

  const int T = 256;
  f32_to_bf16<<<1024, T, 0, stream>>>(Wq, wWq, 1048576);
  f32_to_bf16<<<1024, T, 0, stream>>>(Wk, wWk, 1048576);
  f32_to_bf16<<<1024, T, 0, stream>>>(Wv, wWv, 1048576);
  f32_to_bf16<<<1024, T, 0, stream>>>(Wo, wWo, 1048576);
  f32_to_bf16<<<2048, T, 0, stream>>>(Wff, wWff, 8388608);
  f32_to_bf16<<<2048, T, 0, stream>>>(Wfo, wWfo, 4194304);
  mods_k<<<96, T, 0, stream>>>(sst, temb, modsb);
  norm1_k<<<8192, T, 0, stream>>>(hidden, modsb, normb);

  // QKV / VT / ATTNOUT / FINAL on the 128x256 deep-pipelined path (256 blocks each)
  dim3 g128(8, 32);  // N=2048, M=4096
  gemm128<EPI_QKV><<<g128, 512, 0, stream>>>(normb, 2048, wWq, 2048, bq, 2048, nullptr,
                                             qkvb, 4096, 0, nullptr, nullptr);
  gemm128<EPI_QKV><<<g128, 512, 0, stream>>>(normb, 2048, wWk, 2048, bk, 2048, nullptr,
                                             qkvb, 4096, 2048, nullptr, nullptr);
  // V^T = Wv * norm1^T  (swapped operands -> output [ch][token]); M=2048, N=4096
  gemm128<EPI_VT><<<dim3(16, 16), 512, 0, stream>>>(wWv, 2048, normb, 2048, bv, 2048,
                                                    nullptr, vtb, 4096, 0, nullptr, nullptr);
  qk_ln<<<32768, T, 0, stream>>>(qkvb);
  attn_kernel<<<dim3(32, 16, 2), T, 0, stream>>>(qkvb, vtb, attnb);
  gemm128<EPI_ATTNOUT><<<g128, 512, 0, stream>>>(attnb, 2048, wWo, 2048, bo, 2048, out,
                                                 normb, 2048, 0, hidden, modsb);
  // FF-up GEMMs on the 256x256 deep-pipelined path (N=8192 -> 512 blocks)
  dim3 g256(32, 16);
  gemm256<EPI_GELU><<<g256, 512, 0, stream>>>(normb, 2048, wWff + (size_t)8192 * 2048, 2048,
                                              bff + 8192, 2048, gb, 8192, nullptr);
  gemm256<EPI_MULG><<<g256, 512, 0, stream>>>(normb, 2048, wWff, 2048, bff, 2048, ffgb,
                                              8192, gb);
  gemm128<EPI_FINAL><<<g128, 512, 0, stream>>>(ffgb, 8192, wWfo, 8192, bfo, 8192, out,
                                               nullptr, 0, 0, nullptr, modsb);
}